// Round 4
// baseline (2090.171 us; speedup 1.0000x reference)
//
#include <hip/hip_runtime.h>
#include <math.h>

#define N_NODES 8192
#define N_EDGES 262144
#define INV_SQRT3 0.5773502691896258f

__device__ __forceinline__ float sspf(float x){
    // softplus(x) - ln(2), numerically stable
    float sp = (x > 20.0f) ? x : log1pf(expf(x));
    return sp - 0.6931471805599453f;
}

__device__ __forceinline__ float bcast_lane(float v, int u){
    return __uint_as_float(__builtin_amdgcn_readlane(__float_as_uint(v), u));
}

// ---------------------------------------------------------------------------
// Kernel A: per-node: out = sc (self-connection);
// qd = Wd^T q with all d-stage scales folded in (moves Wd matvec off edges):
//   qd0[v]    = (1/sqrt(2048))        * sum_u q0[u]    * Wd0[u][v]
//   qd1[v][c] = (1/sqrt(2048)/sqrt3) * sum_u q1[u][c] * Wd1[u][v]
// qd layout per node (128): qd0[0..31], qd1 at 32+v*3+c  (matches k layout)
// ---------------------------------------------------------------------------
__global__ __launch_bounds__(128) void node_kernel(
    const float* __restrict__ feats, const float* __restrict__ attrs,
    const float* __restrict__ Wq0, const float* __restrict__ Wq1,
    const float* __restrict__ Wd0, const float* __restrict__ Wd1,
    const float* __restrict__ Ws0, const float* __restrict__ Ws1,
    float* __restrict__ qdbuf, float* __restrict__ out)
{
    int n = blockIdx.x; int t = threadIdx.x;
    __shared__ float sf[128];
    __shared__ float sa[16];
    __shared__ float sq[128];
    sf[t] = feats[n*128 + t];
    if (t < 16) sa[t] = attrs[n*16 + t];
    __syncthreads();
    const float inv_sqrt32 = 0.17677669529663687f;   // 1/sqrt(32)
    const float sc_scale   = 0.04419417382415922f;   // 1/sqrt(32*16)
    const float d_scale    = 0.022097086912079608f;  // 1/sqrt(2*32*32)
    float qv, scv;
    if (t < 32){
        int v = t;
        float acc = 0.f;
        for (int u = 0; u < 32; ++u) acc += sf[u] * Wq0[u*32 + v];
        qv = acc * inv_sqrt32;
        acc = 0.f;
        for (int u = 0; u < 32; ++u){
            float su = sf[u];
            for (int a = 0; a < 16; ++a)
                acc += su * sa[a] * Ws0[(u*16 + a)*32 + v];
        }
        scv = acc * sc_scale;
    } else {
        int k = t - 32; int v = k/3; int c = k - v*3;
        float acc = 0.f;
        for (int u = 0; u < 32; ++u) acc += sf[32 + u*3 + c] * Wq1[u*32 + v];
        qv = acc * inv_sqrt32;
        acc = 0.f;
        for (int u = 0; u < 32; ++u){
            float su = sf[32 + u*3 + c];
            for (int a = 0; a < 16; ++a)
                acc += su * sa[a] * Ws1[(u*16 + a)*32 + v];
        }
        scv = acc * sc_scale;
    }
    sq[t] = qv;
    out[n*128 + t] = scv;
    __syncthreads();

    float qd;
    if (t < 32){
        int v = t;
        float acc = 0.f;
        for (int u = 0; u < 32; ++u) acc += sq[u] * Wd0[u*32 + v];
        qd = acc * d_scale;
    } else {
        int k = t - 32; int v = k/3; int c = k - v*3;
        float acc = 0.f;
        for (int u = 0; u < 32; ++u) acc += sq[32 + u*3 + c] * Wd1[u*32 + v];
        qd = acc * d_scale * INV_SQRT3;
    }
    qdbuf[n*128 + t] = qd;
}

// ---------------------------------------------------------------------------
// Edge pass 1 (register-resident): Wk1+Wk2 in VGPRs, h broadcast via
// v_readlane, uvu fully in registers (column ownership c1=lane(+32), c2=c1+32
// matches uvu's needs), km round-trip through small per-wave LDS for lin,
// d via precomputed qd + shfl reduce. NO barriers, NO block-shared state.
// LDS: 4 waves x 2 edges x 256 dwords = 8 KB.
// ---------------------------------------------------------------------------
__global__ __launch_bounds__(256, 2) void edge_pass1(
    const float* __restrict__ feats, const float* __restrict__ emb,
    const float* __restrict__ eattr, const int* __restrict__ eidx,
    const float* __restrict__ Wk1, const float* __restrict__ Wk2,
    const float* __restrict__ Wlk0, const float* __restrict__ Wlk1,
    const float* __restrict__ qdbuf,
    float* __restrict__ expv_buf, float* __restrict__ zbuf)
{
    __shared__ float lds[2048];
    const int t    = threadIdx.x;
    const int wv   = __builtin_amdgcn_readfirstlane(t >> 6);
    const int lane = t & 63;
    const int rb0  = wv*512;
    const int rb1  = rb0 + 256;

    const bool low = lane < 32;
    const int c1 = low ? lane : lane + 32;   // owned GEMM2 output cols
    const int c2 = c1 + 32;

    // weight preload into VGPRs
    float wk1r[16];
    #pragma unroll
    for (int a = 0; a < 16; ++a) wk1r[a] = Wk1[a*64 + lane];
    float w2a[64], w2b[64];
    #pragma unroll
    for (int u = 0; u < 64; ++u){ w2a[u] = Wk2[u*128 + c1]; w2b[u] = Wk2[u*128 + c2]; }

    // lin-stage lane constants: lane owns outputs o0,o1
    const int p  = lane >> 4;            // 0..3
    const int v0 = (2*lane) & 31;
    const float* __restrict__ wlin = ((p==0)? Wlk0 : Wlk1) + v0;
    const int plane_off = (p==0)? 0 : (64 + (p-1)*64);
    const int o0 = (p==0)? v0     : 32 + v0*3     + (p-1);
    const int o1 = (p==0)? v0 + 1 : 32 + (v0+1)*3 + (p-1);

    const int xsi = low ? lane : (32 + 3*(lane-32));
    const int ebase = (blockIdx.x*4 + wv) * 64;

    for (int it = 0; it < 32; ++it){
        const int e0 = __builtin_amdgcn_readfirstlane(ebase + 2*it);
        const int e1 = e0 + 1;
        const int src0 = eidx[e0], dst0 = eidx[N_EDGES+e0];
        const int src1 = eidx[e1], dst1 = eidx[N_EDGES+e1];

        // ---- GEMM1: h[lane] = ssp(emb@Wk1/4), per edge, in registers ----
        float h0 = 0.f, h1 = 0.f;
        {
            const float4* em0 = (const float4*)(emb + (size_t)e0*16);
            const float4* em1 = (const float4*)(emb + (size_t)e1*16);
            #pragma unroll
            for (int a4 = 0; a4 < 4; ++a4){
                float4 v0e = em0[a4], v1e = em1[a4];
                h0 += v0e.x*wk1r[a4*4+0] + v0e.y*wk1r[a4*4+1] + v0e.z*wk1r[a4*4+2] + v0e.w*wk1r[a4*4+3];
                h1 += v1e.x*wk1r[a4*4+0] + v1e.y*wk1r[a4*4+1] + v1e.z*wk1r[a4*4+2] + v1e.w*wk1r[a4*4+3];
            }
            h0 = sspf(h0*0.25f); h1 = sspf(h1*0.25f);
        }

        // ---- GEMM2: w = h@Wk2/8 via readlane broadcast; accs in regs ----
        float a10=0.f, a20=0.f, a11=0.f, a21=0.f;
        #pragma unroll
        for (int u = 0; u < 64; ++u){
            float s0 = bcast_lane(h0, u);
            float s1 = bcast_lane(h1, u);
            a10 += s0*w2a[u]; a20 += s0*w2b[u];
            a11 += s1*w2a[u]; a21 += s1*w2b[u];
        }
        a10 *= 0.125f; a20 *= 0.125f; a11 *= 0.125f; a21 *= 0.125f;

        // ---- uvu (registers) -> km to LDS (km0 + km1 transposed planes) ----
        {
            const float y00 = eattr[(size_t)e0*4+0], y0a = eattr[(size_t)e0*4+1],
                        y0b = eattr[(size_t)e0*4+2], y0c = eattr[(size_t)e0*4+3];
            const float y10 = eattr[(size_t)e1*4+0], y1a = eattr[(size_t)e1*4+1],
                        y1b = eattr[(size_t)e1*4+2], y1c = eattr[(size_t)e1*4+3];
            const float* fp0 = feats + (size_t)src0*128 + xsi;
            const float* fp1 = feats + (size_t)src1*128 + xsi;
            float xa0 = fp0[0], xb0 = fp0[1], xc0 = fp0[2];
            float xa1 = fp1[0], xb1 = fp1[1], xc1 = fp1[2];

            float wA0 = low ? a10 : a20, wB0 = low ? a20 : a10;
            float wA1 = low ? a11 : a21, wB1 = low ? a21 : a11;

            float dot0 = xa0*y0a + xb0*y0b + xc0*y0c;
            float km00 = wA0 * (low ? xa0*y00 : dot0*INV_SQRT3);
            float pm0  = wB0 * (low ? xa0 : y00);
            float t00  = low ? y0a : xa0, t01 = low ? y0b : xb0, t02 = low ? y0c : xc0;
            lds[rb0 + lane]       = km00;
            lds[rb0 + 64  + lane] = pm0*t00;
            lds[rb0 + 128 + lane] = pm0*t01;
            lds[rb0 + 192 + lane] = pm0*t02;

            float dot1 = xa1*y1a + xb1*y1b + xc1*y1c;
            float km01 = wA1 * (low ? xa1*y10 : dot1*INV_SQRT3);
            float pm1  = wB1 * (low ? xa1 : y10);
            float t10  = low ? y1a : xa1, t11 = low ? y1b : xb1, t12 = low ? y1c : xc1;
            lds[rb1 + lane]       = km01;
            lds[rb1 + 64  + lane] = pm1*t10;
            lds[rb1 + 128 + lane] = pm1*t11;
            lds[rb1 + 192 + lane] = pm1*t12;
        }

        // ---- lin: k = lin(km)/8; lane reads its plane b128, wts from L1 ----
        float l00=0.f,l01=0.f,l10=0.f,l11=0.f;
        #pragma unroll
        for (int u4 = 0; u4 < 16; ++u4){
            float4 m0 = *(const float4*)&lds[rb0 + plane_off + u4*4];
            float4 m1 = *(const float4*)&lds[rb1 + plane_off + u4*4];
            #pragma unroll
            for (int j = 0; j < 4; ++j){
                float2 w2 = *(const float2*)&wlin[(u4*4+j)*32];
                float mm0 = (&m0.x)[j], mm1 = (&m1.x)[j];
                l00 += mm0*w2.x; l01 += mm0*w2.y;
                l10 += mm1*w2.x; l11 += mm1*w2.y;
            }
        }
        l00 *= 0.125f; l01 *= 0.125f; l10 *= 0.125f; l11 *= 0.125f;

        // ---- d: part = k.qd[dst] (scales folded into qd); shfl reduce ----
        {
            const float* qd0p = qdbuf + (size_t)dst0*128;
            const float* qd1p = qdbuf + (size_t)dst1*128;
            float part0 = l00*qd0p[o0] + l01*qd0p[o1];
            float part1 = l10*qd1p[o0] + l11*qd1p[o1];
            #pragma unroll
            for (int off = 32; off > 0; off >>= 1){
                part0 += __shfl_xor(part0, off);
                part1 += __shfl_xor(part1, off);
            }
            if (lane == 0){
                // cutoff const: diff = pos[src]-pos[src] == 0 (reference bug)
                float ev0 = 0.9048374180359595f * expf(part0);
                float ev1 = 0.9048374180359595f * expf(part1);
                expv_buf[e0] = ev0;
                expv_buf[e1] = ev1;
                atomicAdd(&zbuf[dst0], ev0);
                atomicAdd(&zbuf[dst1], ev1);
            }
        }
    }
}

// ---------------------------------------------------------------------------
// Edge pass 2: v-path, same register structure; epilogue = sqrt(alpha)*v
// atomically into out[dst]. No d-stage.
// ---------------------------------------------------------------------------
__global__ __launch_bounds__(256, 2) void edge_pass2(
    const float* __restrict__ feats, const float* __restrict__ emb,
    const float* __restrict__ eattr, const int* __restrict__ eidx,
    const float* __restrict__ Wv1, const float* __restrict__ Wv2,
    const float* __restrict__ Wlv0, const float* __restrict__ Wlv1,
    const float* __restrict__ expv_buf, const float* __restrict__ zbuf,
    float* __restrict__ out)
{
    __shared__ float lds[2048];
    const int t    = threadIdx.x;
    const int wv   = __builtin_amdgcn_readfirstlane(t >> 6);
    const int lane = t & 63;
    const int rb0  = wv*512;
    const int rb1  = rb0 + 256;

    const bool low = lane < 32;
    const int c1 = low ? lane : lane + 32;
    const int c2 = c1 + 32;

    float wk1r[16];
    #pragma unroll
    for (int a = 0; a < 16; ++a) wk1r[a] = Wv1[a*64 + lane];
    float w2a[64], w2b[64];
    #pragma unroll
    for (int u = 0; u < 64; ++u){ w2a[u] = Wv2[u*128 + c1]; w2b[u] = Wv2[u*128 + c2]; }

    const int p  = lane >> 4;
    const int v0 = (2*lane) & 31;
    const float* __restrict__ wlin = ((p==0)? Wlv0 : Wlv1) + v0;
    const int plane_off = (p==0)? 0 : (64 + (p-1)*64);
    const int o0 = (p==0)? v0     : 32 + v0*3     + (p-1);
    const int o1 = (p==0)? v0 + 1 : 32 + (v0+1)*3 + (p-1);

    const int xsi = low ? lane : (32 + 3*(lane-32));
    const int ebase = (blockIdx.x*4 + wv) * 64;

    for (int it = 0; it < 32; ++it){
        const int e0 = __builtin_amdgcn_readfirstlane(ebase + 2*it);
        const int e1 = e0 + 1;
        const int src0 = eidx[e0], dst0 = eidx[N_EDGES+e0];
        const int src1 = eidx[e1], dst1 = eidx[N_EDGES+e1];

        float h0 = 0.f, h1 = 0.f;
        {
            const float4* em0 = (const float4*)(emb + (size_t)e0*16);
            const float4* em1 = (const float4*)(emb + (size_t)e1*16);
            #pragma unroll
            for (int a4 = 0; a4 < 4; ++a4){
                float4 v0e = em0[a4], v1e = em1[a4];
                h0 += v0e.x*wk1r[a4*4+0] + v0e.y*wk1r[a4*4+1] + v0e.z*wk1r[a4*4+2] + v0e.w*wk1r[a4*4+3];
                h1 += v1e.x*wk1r[a4*4+0] + v1e.y*wk1r[a4*4+1] + v1e.z*wk1r[a4*4+2] + v1e.w*wk1r[a4*4+3];
            }
            h0 = sspf(h0*0.25f); h1 = sspf(h1*0.25f);
        }

        float a10=0.f, a20=0.f, a11=0.f, a21=0.f;
        #pragma unroll
        for (int u = 0; u < 64; ++u){
            float s0 = bcast_lane(h0, u);
            float s1 = bcast_lane(h1, u);
            a10 += s0*w2a[u]; a20 += s0*w2b[u];
            a11 += s1*w2a[u]; a21 += s1*w2b[u];
        }
        a10 *= 0.125f; a20 *= 0.125f; a11 *= 0.125f; a21 *= 0.125f;

        {
            const float y00 = eattr[(size_t)e0*4+0], y0a = eattr[(size_t)e0*4+1],
                        y0b = eattr[(size_t)e0*4+2], y0c = eattr[(size_t)e0*4+3];
            const float y10 = eattr[(size_t)e1*4+0], y1a = eattr[(size_t)e1*4+1],
                        y1b = eattr[(size_t)e1*4+2], y1c = eattr[(size_t)e1*4+3];
            const float* fp0 = feats + (size_t)src0*128 + xsi;
            const float* fp1 = feats + (size_t)src1*128 + xsi;
            float xa0 = fp0[0], xb0 = fp0[1], xc0 = fp0[2];
            float xa1 = fp1[0], xb1 = fp1[1], xc1 = fp1[2];

            float wA0 = low ? a10 : a20, wB0 = low ? a20 : a10;
            float wA1 = low ? a11 : a21, wB1 = low ? a21 : a11;

            float dot0 = xa0*y0a + xb0*y0b + xc0*y0c;
            float km00 = wA0 * (low ? xa0*y00 : dot0*INV_SQRT3);
            float pm0  = wB0 * (low ? xa0 : y00);
            float t00  = low ? y0a : xa0, t01 = low ? y0b : xb0, t02 = low ? y0c : xc0;
            lds[rb0 + lane]       = km00;
            lds[rb0 + 64  + lane] = pm0*t00;
            lds[rb0 + 128 + lane] = pm0*t01;
            lds[rb0 + 192 + lane] = pm0*t02;

            float dot1 = xa1*y1a + xb1*y1b + xc1*y1c;
            float km01 = wA1 * (low ? xa1*y10 : dot1*INV_SQRT3);
            float pm1  = wB1 * (low ? xa1 : y10);
            float t10  = low ? y1a : xa1, t11 = low ? y1b : xb1, t12 = low ? y1c : xc1;
            lds[rb1 + lane]       = km01;
            lds[rb1 + 64  + lane] = pm1*t10;
            lds[rb1 + 128 + lane] = pm1*t11;
            lds[rb1 + 192 + lane] = pm1*t12;
        }

        float l00=0.f,l01=0.f,l10=0.f,l11=0.f;
        #pragma unroll
        for (int u4 = 0; u4 < 16; ++u4){
            float4 m0 = *(const float4*)&lds[rb0 + plane_off + u4*4];
            float4 m1 = *(const float4*)&lds[rb1 + plane_off + u4*4];
            #pragma unroll
            for (int j = 0; j < 4; ++j){
                float2 w2 = *(const float2*)&wlin[(u4*4+j)*32];
                float mm0 = (&m0.x)[j], mm1 = (&m1.x)[j];
                l00 += mm0*w2.x; l01 += mm0*w2.y;
                l10 += mm1*w2.x; l11 += mm1*w2.y;
            }
        }
        l00 *= 0.125f; l01 *= 0.125f; l10 *= 0.125f; l11 *= 0.125f;

        // ---- epilogue: coef = sqrt(relu(alpha)); atomic scatter-add ----
        {
            float ev0 = expv_buf[e0], ev1 = expv_buf[e1];
            float z0 = zbuf[dst0];  z0 = (z0 == 0.f) ? 1.f : z0;
            float z1 = zbuf[dst1];  z1 = (z1 == 0.f) ? 1.f : z1;
            float coef0 = sqrtf(fmaxf(ev0/z0, 0.f));
            float coef1 = sqrtf(fmaxf(ev1/z1, 0.f));
            float* op0 = out + (size_t)dst0*128;
            float* op1 = out + (size_t)dst1*128;
            atomicAdd(op0 + o0, coef0*l00);
            atomicAdd(op0 + o1, coef0*l01);
            atomicAdd(op1 + o0, coef1*l10);
            atomicAdd(op1 + o1, coef1*l11);
        }
    }
}

extern "C" void kernel_launch(void* const* d_in, const int* in_sizes, int n_in,
                              void* d_out, int out_size, void* d_ws, size_t ws_size,
                              hipStream_t stream)
{
    const float* feats = (const float*)d_in[0];
    const float* attrs = (const float*)d_in[1];
    const float* emb   = (const float*)d_in[2];
    const float* eattr = (const float*)d_in[3];
    // d_in[4] positions: unused (reference computes positions[src]-positions[src] == 0)
    const float* Wq0  = (const float*)d_in[5];
    const float* Wq1  = (const float*)d_in[6];
    const float* Wk1  = (const float*)d_in[7];
    const float* Wk2  = (const float*)d_in[8];
    const float* Wv1  = (const float*)d_in[9];
    const float* Wv2  = (const float*)d_in[10];
    const float* Wlk0 = (const float*)d_in[11];
    const float* Wlk1 = (const float*)d_in[12];
    const float* Wlv0 = (const float*)d_in[13];
    const float* Wlv1 = (const float*)d_in[14];
    const float* Wd0  = (const float*)d_in[15];
    const float* Wd1  = (const float*)d_in[16];
    const float* Ws0  = (const float*)d_in[17];
    const float* Ws1  = (const float*)d_in[18];
    const int*   eidx = (const int*)d_in[19];

    float* out   = (float*)d_out;
    float* qdbuf = (float*)d_ws;                  // N*128 floats (qd = Wd^T q, scaled)
    float* expv  = qdbuf + (size_t)N_NODES*128;   // E floats
    float* zbuf  = expv + (size_t)N_EDGES;        // N floats

    hipMemsetAsync(zbuf, 0, N_NODES*sizeof(float), stream);
    node_kernel<<<N_NODES, 128, 0, stream>>>(feats, attrs, Wq0, Wq1, Wd0, Wd1,
                                             Ws0, Ws1, qdbuf, out);
    edge_pass1<<<N_EDGES/256, 256, 0, stream>>>(feats, emb, eattr, eidx,
                                                Wk1, Wk2, Wlk0, Wlk1,
                                                qdbuf, expv, zbuf);
    edge_pass2<<<N_EDGES/256, 256, 0, stream>>>(feats, emb, eattr, eidx,
                                                Wv1, Wv2, Wlv0, Wlv1,
                                                expv, zbuf, out);
}